// Round 5
// baseline (146.607 us; speedup 1.0000x reference)
//
#include <hip/hip_runtime.h>

// PositionalEmbedding: out[node, t*32 + j] = (child_pos(ancestor_t(node)) == j)
// N = 262144, n = 32, k = 16. Output float32 [N, 512] = 512 MiB, write-BW-bound.
// R5: scalar-path expand. One wave-iteration = one half-row (1024 B); the 8
// code bytes are wave-uniform -> s_load_dwordx2 (scalar cache), so the vector
// memory pipe sees ONLY stores (fill-shaped).

#define NN 32   // one-hot width (n)
#define KK 16   // ancestor depth (k)
#define NPB 256

typedef float f32x4 __attribute__((ext_vector_type(4)));

// ---- Kernel 0: merge parent/child_pos into one int2 table ----
__global__ __launch_bounds__(256) void pe_merge(
    const int* __restrict__ parents,
    const int* __restrict__ child_pos,
    int2* __restrict__ comb, int Np1)
{
    const int i = blockIdx.x * 256 + threadIdx.x;
    if (i < Np1) comb[i] = make_int2(parents[i], child_pos[i]);
}

// ---- Kernel 1: 16-step chase -> 16 packed code bytes per node ----
__global__ __launch_bounds__(256) void pe_codes(
    const int2* __restrict__ comb,
    uint4* __restrict__ codes_out, int N)
{
    const int node = blockIdx.x * blockDim.x + threadIdx.x;
    if (node >= N) return;
    unsigned int packed[KK / 4];
    int cur = node;
    #pragma unroll
    for (int w = 0; w < KK / 4; ++w) {
        unsigned int u = 0;
        #pragma unroll
        for (int b = 0; b < 4; ++b) {
            const int2 pc = comb[cur];
            const unsigned int byte = (pc.y < NN) ? (unsigned int)pc.y : 0xFFu;
            u |= byte << (8 * b);
            cur = pc.x;
        }
        packed[w] = u;
    }
    codes_out[node] = make_uint4(packed[0], packed[1], packed[2], packed[3]);
}

// ---- Kernel 2: scalar-path streaming expand ----
// half-row hr = node*2 + half covers bytes [hr*1024, hr*1024+1024) of out.
// Lane l writes float4 #l; needs code byte t = half*8 + (l>>3), i.e. byte
// (l>>3) of the wave-uniform qword codes8[hr].
__global__ __launch_bounds__(256) void pe_expand_s(
    const unsigned long long* __restrict__ codes8,
    f32x4* __restrict__ out4, int total_hr)
{
    const int lane = threadIdx.x & 63;
    const int wid  = (int)((blockIdx.x * blockDim.x + threadIdx.x) >> 6);
    const int nw   = (int)((gridDim.x * blockDim.x) >> 6);
    const int tl8  = (lane >> 3) * 8;     // shift to select this lane's byte
    const int q4   = (lane & 7) * 4;      // this lane's one-hot quad base

    #pragma unroll 4
    for (int hr = wid; hr < total_hr; hr += nw) {
        const int hr_s = __builtin_amdgcn_readfirstlane(hr);   // force SGPR
        const unsigned long long c8 = codes8[hr_s];            // s_load_dwordx2
        const int code = (int)((c8 >> tl8) & 0xFFu);
        f32x4 v;
        v.x = (code == q4    ) ? 1.0f : 0.0f;
        v.y = (code == q4 + 1) ? 1.0f : 0.0f;
        v.z = (code == q4 + 2) ? 1.0f : 0.0f;
        v.w = (code == q4 + 3) ? 1.0f : 0.0f;
        out4[(size_t)hr_s * 64 + lane] = v;                    // coalesced 1 KiB/wave
    }
}

// ---- Fallback: proven single-kernel path (R1, 114 us) if ws too small ----
__global__ __launch_bounds__(256, 8) void pe_kernel(
    const int* __restrict__ parents,
    const int* __restrict__ child_pos,
    float* __restrict__ out, int N)
{
    __shared__ unsigned char codes[NPB * KK];
    const int tid   = threadIdx.x;
    const int node0 = blockIdx.x * NPB;
    const int node  = node0 + tid;

    unsigned int packed[KK / 4];
    if (node < N) {
        int cur = node;
        #pragma unroll
        for (int w = 0; w < KK / 4; ++w) {
            unsigned int u = 0;
            #pragma unroll
            for (int b = 0; b < 4; ++b) {
                int cp = child_pos[cur];
                unsigned int byte = (cp < NN) ? (unsigned int)cp : 0xFFu;
                u |= byte << (8 * b);
                cur = parents[cur];
            }
            packed[w] = u;
        }
    } else {
        #pragma unroll
        for (int w = 0; w < KK / 4; ++w) packed[w] = 0xFFFFFFFFu;
    }
    *reinterpret_cast<uint4*>(&codes[tid * KK]) =
        make_uint4(packed[0], packed[1], packed[2], packed[3]);
    __syncthreads();

    const int t_seg = (tid >> 3) & 15;
    const int q4    = (tid & 7) * 4;
    const int hi    = tid >> 7;
    float4* out4 = reinterpret_cast<float4*>(out) + (size_t)node0 * (NN * KK / 4);

    #pragma unroll 4
    for (int iter = 0; iter < (NPB * KK * NN / 4) / 256; ++iter) {
        const int nl   = 2 * iter + hi;
        const int code = codes[nl * KK + t_seg];
        float4 v;
        v.x = (code == q4    ) ? 1.0f : 0.0f;
        v.y = (code == q4 + 1) ? 1.0f : 0.0f;
        v.z = (code == q4 + 2) ? 1.0f : 0.0f;
        v.w = (code == q4 + 3) ? 1.0f : 0.0f;
        if (node0 + nl < N)
            out4[(size_t)iter * 256 + tid] = v;
    }
}

extern "C" void kernel_launch(void* const* d_in, const int* in_sizes, int n_in,
                              void* d_out, int out_size, void* d_ws, size_t ws_size,
                              hipStream_t stream) {
    const int* parents   = (const int*)d_in[0];
    const int* child_pos = (const int*)d_in[1];
    float* out = (float*)d_out;

    const int N   = in_sizes[0] - 1;              // 262144
    const int Np1 = N + 1;

    const size_t comb_bytes  = (size_t)Np1 * sizeof(int2);
    const size_t codes_off   = (comb_bytes + 15) & ~(size_t)15;
    const size_t need        = codes_off + (size_t)N * KK;

    if (ws_size >= need) {
        char* ws = (char*)d_ws;
        int2* comb   = (int2*)ws;
        uint4* codes = (uint4*)(ws + codes_off);

        pe_merge<<<(Np1 + 255) / 256, 256, 0, stream>>>(
            parents, child_pos, comb, Np1);
        pe_codes<<<(N + 255) / 256, 256, 0, stream>>>(comb, codes, N);

        const int total_hr = N * 2;               // 524288 half-rows
        pe_expand_s<<<1024, 256, 0, stream>>>(
            (const unsigned long long*)codes, (f32x4*)out, total_hr);
    } else {
        pe_kernel<<<(N + NPB - 1) / NPB, 256, 0, stream>>>(
            parents, child_pos, out, N);
    }
}

// Round 6
// 111.318 us; speedup vs baseline: 1.3170x; 1.3170x over previous
//
#include <hip/hip_runtime.h>

// PositionalEmbedding: out[node, t*32 + j] = (child_pos(ancestor_t(node)) == j)
// N = 262144, n = 32, k = 16. Output float32 [N, 512] = 512 MiB, write-BW-bound.
// R6: load-free store loop. Each wave owns 64 node-rows; codes live in the
// owning lane's VGPRs (packed uint4 from the chase). The store loop reads them
// via v_readlane (pure VALU, no lgkmcnt/vmcnt wait) -> store issue is
// continuous, exactly like __amd_rocclr_fillBufferAligned (6.8 TB/s).

#define NN 32   // one-hot width (n)
#define KK 16   // ancestor depth (k)

typedef float f32x4 __attribute__((ext_vector_type(4)));

__global__ __launch_bounds__(256) void pe_fused_rl(
    const int* __restrict__ parents,
    const int* __restrict__ child_pos,
    f32x4* __restrict__ out4, int N)
{
    const int lane  = (int)(threadIdx.x & 63);
    const int wid   = (int)((blockIdx.x * blockDim.x + threadIdx.x) >> 6);
    const int wbase = wid * 64;          // first node-row of this wave
    const int node  = wbase + lane;      // this lane chases this node

    // ---- Phase A: per-lane 16-step ancestor chase -> 4 packed dwords ----
    // byte t of (c[t>>2] >> 8*(t&3)) = clamped child_pos of ancestor_t(node)
    unsigned int c[4];
    {
        int cur = (node < N) ? node : N; // sentinel-safe (exact grid anyway)
        #pragma unroll
        for (int w = 0; w < 4; ++w) {
            unsigned int u = 0;
            #pragma unroll
            for (int b = 0; b < 4; ++b) {
                const int cp = child_pos[cur];               // independent
                const unsigned int byte = (cp < NN) ? (unsigned int)cp : 0xFFu;
                u |= byte << (8 * b);
                cur = parents[cur];                          // dependent chain
            }
            c[w] = u;
        }
    }

    // ---- Phase B: wait-free store loop over the wave's 64 rows ----
    // Row r: lane l writes float4 (h*64+l) of row (wbase+r), h in {0,1}.
    //   t = h*8 + (l>>3); code dword = h*2 + (l>>5); byte = (l>>3)&3.
    const bool hi32 = (lane >= 32);
    const int  sh   = ((lane >> 3) & 3) * 8;   // byte-in-dword shift
    const int  q4   = (lane & 7) * 4;          // one-hot quad base

    f32x4* wout = out4 + (size_t)wbase * 128 + lane;

    #pragma unroll 4
    for (int r = 0; r < 64; ++r) {
        // codes of node (wbase + r) -- pulled from lane r, no memory op
        const unsigned s0 = (unsigned)__builtin_amdgcn_readlane((int)c[0], r);
        const unsigned s1 = (unsigned)__builtin_amdgcn_readlane((int)c[1], r);
        const unsigned s2 = (unsigned)__builtin_amdgcn_readlane((int)c[2], r);
        const unsigned s3 = (unsigned)__builtin_amdgcn_readlane((int)c[3], r);

        const int code0 = (int)(((hi32 ? s1 : s0) >> sh) & 0xFFu);
        const int code1 = (int)(((hi32 ? s3 : s2) >> sh) & 0xFFu);

        f32x4 v0, v1;
        v0.x = (code0 == q4    ) ? 1.0f : 0.0f;
        v0.y = (code0 == q4 + 1) ? 1.0f : 0.0f;
        v0.z = (code0 == q4 + 2) ? 1.0f : 0.0f;
        v0.w = (code0 == q4 + 3) ? 1.0f : 0.0f;
        v1.x = (code1 == q4    ) ? 1.0f : 0.0f;
        v1.y = (code1 == q4 + 1) ? 1.0f : 0.0f;
        v1.z = (code1 == q4 + 2) ? 1.0f : 0.0f;
        v1.w = (code1 == q4 + 3) ? 1.0f : 0.0f;

        wout[(size_t)r * 128]      = v0;   // 1 KiB/wave, coalesced
        wout[(size_t)r * 128 + 64] = v1;   // 1 KiB/wave, coalesced
    }
}

extern "C" void kernel_launch(void* const* d_in, const int* in_sizes, int n_in,
                              void* d_out, int out_size, void* d_ws, size_t ws_size,
                              hipStream_t stream) {
    const int* parents   = (const int*)d_in[0];
    const int* child_pos = (const int*)d_in[1];
    f32x4* out4 = (f32x4*)d_out;

    const int N = in_sizes[0] - 1;                 // 262144
    // one wave per 64 nodes: N/64 = 4096 waves = 1024 blocks of 256
    const int n_waves = (N + 63) / 64;
    const int grid    = (n_waves + 3) / 4;

    pe_fused_rl<<<grid, 256, 0, stream>>>(parents, child_pos, out4, N);
}